// Round 17
// baseline (467.056 us; speedup 1.0000x reference)
//
#include <hip/hip_runtime.h>
#include <math.h>

#define D_FEAT 12544
#define NC 1000
#define RB 16          // rows per k4 tier
#define S8 8           // global D slices
#define DBIG 1568      // D_FEAT / S8
#define DSUB 196       // LDS sub-chunk
#define NSUB 8         // DBIG / DSUB
#define NIT4 49        // DSUB / 4

// ---------------- K1: conv1(1->32,3x3,VALID)+ReLU+maxpool2 -> h1[128,31,31,32]
__global__ __launch_bounds__(256) void k1_conv1(
    const float* __restrict__ x, const float* __restrict__ w,
    const float* __restrict__ bias, float* __restrict__ h1,
    int* __restrict__ cnt)
{
    // zero routing counters (stream-ordered before k3)
    if (blockIdx.x == 0 && threadIdx.x < 8) cnt[threadIdx.x] = 0;

    int co  = threadIdx.x & 31;
    int pxi = threadIdx.x >> 5;          // 0..7
    int blk = blockIdx.x;
    int pxg = blk & 3;
    int py  = (blk >> 2) % 31;
    int b   = blk / (31 * 4);
    int px  = pxg * 8 + pxi;
    if (px >= 31) return;

    float wr[9];
#pragma unroll
    for (int t = 0; t < 9; ++t) wr[t] = w[t * 32 + co];
    float bb = bias[co];

    float in[4][4];
    const float* xb = x + ((size_t)(b * 64 + 2 * py) * 64 + 2 * px);
#pragma unroll
    for (int r = 0; r < 4; ++r)
#pragma unroll
        for (int c = 0; c < 4; ++c)
            in[r][c] = xb[r * 64 + c];

    float a00 = 0.f, a01 = 0.f, a10 = 0.f, a11 = 0.f;
#pragma unroll
    for (int ky = 0; ky < 3; ++ky)
#pragma unroll
        for (int kx = 0; kx < 3; ++kx) {
            float wv = wr[ky * 3 + kx];
            a00 = fmaf(in[ky][kx],     wv, a00);
            a01 = fmaf(in[ky][kx + 1], wv, a01);
            a10 = fmaf(in[ky + 1][kx], wv, a10);
            a11 = fmaf(in[ky + 1][kx + 1], wv, a11);
        }
    a00 = fmaxf(a00 + bb, 0.f);
    a01 = fmaxf(a01 + bb, 0.f);
    a10 = fmaxf(a10 + bb, 0.f);
    a11 = fmaxf(a11 + bb, 0.f);
    float v = fmaxf(fmaxf(a00, a01), fmaxf(a10, a11));
    h1[((size_t)(b * 31 + py) * 31 + px) * 32 + co] = v;
}

// ---------------- K2: conv2(32->64,3x3,VALID)+ReLU+maxpool2 -> h[128,14,14,64]
__global__ __launch_bounds__(448) void k2_conv2(
    const float* __restrict__ h1, const float* __restrict__ w2,
    const float* __restrict__ b2, float* __restrict__ h)
{
    __shared__ float wl[9 * 32 * 32];    // [tap][ci][co_local] 36864 B

    int co  = threadIdx.x & 31;
    int px  = threadIdx.x >> 5;          // 0..13
    int blk = blockIdx.x;
    int cob = blk & 1;
    int py  = (blk >> 1) % 14;
    int b   = blk / 28;

    for (int i = threadIdx.x; i < 9 * 32 * 32; i += 448) {
        int tapci = i >> 5;
        int col   = i & 31;
        wl[i] = w2[tapci * 64 + cob * 32 + col];
    }
    __syncthreads();

    float acc00 = 0.f, acc01 = 0.f, acc10 = 0.f, acc11 = 0.f;
    const float* base = h1 + ((size_t)(b * 31 + 2 * py) * 31 + 2 * px) * 32;

    for (int q = 0; q < 8; ++q) {
        float4 in4[4][4];
#pragma unroll
        for (int r = 0; r < 4; ++r)
#pragma unroll
            for (int c = 0; c < 4; ++c)
                in4[r][c] = *(const float4*)(base + (r * 31 + c) * 32 + q * 4);

#pragma unroll
        for (int ky = 0; ky < 3; ++ky)
#pragma unroll
            for (int kx = 0; kx < 3; ++kx) {
                int tap = ky * 3 + kx;
                const float* wp = &wl[(tap * 32 + q * 4) * 32 + co];
                float w0 = wp[0];
                float w1 = wp[32];
                float w2v = wp[64];
                float w3 = wp[96];
                acc00 = fmaf(in4[ky][kx].x, w0, acc00);
                acc00 = fmaf(in4[ky][kx].y, w1, acc00);
                acc00 = fmaf(in4[ky][kx].z, w2v, acc00);
                acc00 = fmaf(in4[ky][kx].w, w3, acc00);
                acc01 = fmaf(in4[ky][kx + 1].x, w0, acc01);
                acc01 = fmaf(in4[ky][kx + 1].y, w1, acc01);
                acc01 = fmaf(in4[ky][kx + 1].z, w2v, acc01);
                acc01 = fmaf(in4[ky][kx + 1].w, w3, acc01);
                acc10 = fmaf(in4[ky + 1][kx].x, w0, acc10);
                acc10 = fmaf(in4[ky + 1][kx].y, w1, acc10);
                acc10 = fmaf(in4[ky + 1][kx].z, w2v, acc10);
                acc10 = fmaf(in4[ky + 1][kx].w, w3, acc10);
                acc11 = fmaf(in4[ky + 1][kx + 1].x, w0, acc11);
                acc11 = fmaf(in4[ky + 1][kx + 1].y, w1, acc11);
                acc11 = fmaf(in4[ky + 1][kx + 1].z, w2v, acc11);
                acc11 = fmaf(in4[ky + 1][kx + 1].w, w3, acc11);
            }
    }

    float bb = b2[cob * 32 + co];
    acc00 = fmaxf(acc00 + bb, 0.f);
    acc01 = fmaxf(acc01 + bb, 0.f);
    acc10 = fmaxf(acc10 + bb, 0.f);
    acc11 = fmaxf(acc11 + bb, 0.f);
    float v = fmaxf(fmaxf(acc00, acc01), fmaxf(acc10, acc11));
    h[(size_t)b * D_FEAT + (py * 14 + px) * 64 + cob * 32 + co] = v;
}

// ---------------- K3: gate logits (vectorized float4) + softmax + top2 + routing
__global__ __launch_bounds__(256) void k3_gate(
    const float* __restrict__ h, const float* __restrict__ gw,
    const float* __restrict__ gb, int* __restrict__ cnt,
    int* __restrict__ rowIdx, float* __restrict__ rowW,
    int* __restrict__ rowK, int* __restrict__ top2e, float* __restrict__ top2w)
{
    int b = blockIdx.x;
    int tid = threadIdx.x;
    float acc[8];
#pragma unroll
    for (int e = 0; e < 8; ++e) acc[e] = 0.f;

    const float* hb = h + (size_t)b * D_FEAT;
    for (int i4 = tid; i4 < D_FEAT / 4; i4 += 256) {
        float4 hv = *(const float4*)(hb + i4 * 4);
        const float* gp = gw + (size_t)i4 * 32;
        float4 g0 = *(const float4*)(gp);
        float4 g1 = *(const float4*)(gp + 4);
        float4 g2 = *(const float4*)(gp + 8);
        float4 g3 = *(const float4*)(gp + 12);
        float4 g4 = *(const float4*)(gp + 16);
        float4 g5 = *(const float4*)(gp + 20);
        float4 g6 = *(const float4*)(gp + 24);
        float4 g7 = *(const float4*)(gp + 28);

        acc[0] = fmaf(hv.x, g0.x, acc[0]); acc[0] = fmaf(hv.y, g2.x, acc[0]);
        acc[0] = fmaf(hv.z, g4.x, acc[0]); acc[0] = fmaf(hv.w, g6.x, acc[0]);
        acc[1] = fmaf(hv.x, g0.y, acc[1]); acc[1] = fmaf(hv.y, g2.y, acc[1]);
        acc[1] = fmaf(hv.z, g4.y, acc[1]); acc[1] = fmaf(hv.w, g6.y, acc[1]);
        acc[2] = fmaf(hv.x, g0.z, acc[2]); acc[2] = fmaf(hv.y, g2.z, acc[2]);
        acc[2] = fmaf(hv.z, g4.z, acc[2]); acc[2] = fmaf(hv.w, g6.z, acc[2]);
        acc[3] = fmaf(hv.x, g0.w, acc[3]); acc[3] = fmaf(hv.y, g2.w, acc[3]);
        acc[3] = fmaf(hv.z, g4.w, acc[3]); acc[3] = fmaf(hv.w, g6.w, acc[3]);
        acc[4] = fmaf(hv.x, g1.x, acc[4]); acc[4] = fmaf(hv.y, g3.x, acc[4]);
        acc[4] = fmaf(hv.z, g5.x, acc[4]); acc[4] = fmaf(hv.w, g7.x, acc[4]);
        acc[5] = fmaf(hv.x, g1.y, acc[5]); acc[5] = fmaf(hv.y, g3.y, acc[5]);
        acc[5] = fmaf(hv.z, g5.y, acc[5]); acc[5] = fmaf(hv.w, g7.y, acc[5]);
        acc[6] = fmaf(hv.x, g1.z, acc[6]); acc[6] = fmaf(hv.y, g3.z, acc[6]);
        acc[6] = fmaf(hv.z, g5.z, acc[6]); acc[6] = fmaf(hv.w, g7.z, acc[6]);
        acc[7] = fmaf(hv.x, g1.w, acc[7]); acc[7] = fmaf(hv.y, g3.w, acc[7]);
        acc[7] = fmaf(hv.z, g5.w, acc[7]); acc[7] = fmaf(hv.w, g7.w, acc[7]);
    }

#pragma unroll
    for (int e = 0; e < 8; ++e) {
        float v = acc[e];
        v += __shfl_down(v, 32, 64);
        v += __shfl_down(v, 16, 64);
        v += __shfl_down(v, 8, 64);
        v += __shfl_down(v, 4, 64);
        v += __shfl_down(v, 2, 64);
        v += __shfl_down(v, 1, 64);
        acc[e] = v;
    }

    __shared__ float sm[4][8];
    int wid = tid >> 6, ln = tid & 63;
    if (ln == 0) {
#pragma unroll
        for (int e = 0; e < 8; ++e) sm[wid][e] = acc[e];
    }
    __syncthreads();

    if (tid == 0) {
        float lg[8], p[8];
        float m = -1e30f;
#pragma unroll
        for (int e = 0; e < 8; ++e) {
            lg[e] = sm[0][e] + sm[1][e] + sm[2][e] + sm[3][e] + gb[e];
            m = fmaxf(m, lg[e]);
        }
        float s = 0.f;
#pragma unroll
        for (int e = 0; e < 8; ++e) { p[e] = expf(lg[e] - m); s += p[e]; }
        float inv = 1.f / s;
#pragma unroll
        for (int e = 0; e < 8; ++e) p[e] *= inv;

        int i0 = 0;
#pragma unroll
        for (int e = 1; e < 8; ++e) if (p[e] > p[i0]) i0 = e;
        int i1 = (i0 == 0) ? 1 : 0;
#pragma unroll
        for (int e = 0; e < 8; ++e) if (e != i0 && p[e] > p[i1]) i1 = e;

        int pos0 = atomicAdd(&cnt[i0], 1);
        rowIdx[i0 * 128 + pos0] = b;
        rowW[i0 * 128 + pos0] = p[i0];
        rowK[i0 * 128 + pos0] = 0;
        int pos1 = atomicAdd(&cnt[i1], 1);
        rowIdx[i1 * 128 + pos1] = b;
        rowW[i1 * 128 + pos1] = p[i1];
        rowK[i1 * 128 + pos1] = 1;

        top2e[b * 2]     = i0;
        top2e[b * 2 + 1] = i1;
        top2w[b * 2]     = p[i0];
        top2w[b * 2 + 1] = p[i1];
    }
}

#define FMA_ROW(A, HV, W0, W1, W2, W3)                          \
    do {                                                        \
        (A).x = fmaf((HV).x, (W0).x, (A).x);                    \
        (A).x = fmaf((HV).y, (W1).x, (A).x);                    \
        (A).x = fmaf((HV).z, (W2).x, (A).x);                    \
        (A).x = fmaf((HV).w, (W3).x, (A).x);                    \
        (A).y = fmaf((HV).x, (W0).y, (A).y);                    \
        (A).y = fmaf((HV).y, (W1).y, (A).y);                    \
        (A).y = fmaf((HV).z, (W2).y, (A).y);                    \
        (A).y = fmaf((HV).w, (W3).y, (A).y);                    \
        (A).z = fmaf((HV).x, (W0).z, (A).z);                    \
        (A).z = fmaf((HV).y, (W1).z, (A).z);                    \
        (A).z = fmaf((HV).z, (W2).z, (A).z);                    \
        (A).z = fmaf((HV).w, (W3).z, (A).z);                    \
        (A).w = fmaf((HV).x, (W0).w, (A).w);                    \
        (A).w = fmaf((HV).y, (W1).w, (A).w);                    \
        (A).w = fmaf((HV).z, (W2).w, (A).w);                    \
        (A).w = fmaf((HV).w, (W3).w, (A).w);                    \
    } while (0)

// ---------------- K4: grouped expert GEMM — 6.27 MB contiguous W streams
// grid = rc(HIGH, 8, sparse) x e(8) x s(LOW 3 bits -> XCD-uniform) = 512 blocks.
// Each block streams W[(e, s*1568 .. s*1568+1568), all 1000 cols] contiguously
// (6.27 MB, no restarts); h staged per 196-d sub-chunk (12.5 KB LDS, 8 phases).
__global__ __launch_bounds__(256) void k4_expert(
    const float* __restrict__ h, const float* __restrict__ ew,
    const int* __restrict__ cnt, const int* __restrict__ rowIdx,
    const float* __restrict__ rowW, const int* __restrict__ rowK,
    float* __restrict__ part)
{
    __shared__ float h_lds[RB * DSUB];          // 12544 B
    __shared__ int   roff_s[RB];

    int tid = threadIdx.x;
    int bid = blockIdx.x;
    int s  = bid & 7;                    // LOW bits: uniform across XCDs
    int e  = (bid >> 3) & 7;
    int rc = bid >> 6;                   // HIGH bits: sparse early-exit (0..7)

    int n = cnt[e];
    int rbase = rc * RB;
    if (rbase >= n) return;
    int nrows = n - rbase; if (nrows > RB) nrows = RB;

    if (tid < RB) {
        roff_s[tid] = (tid < nrows) ? rowIdx[e * 128 + rbase + tid] * D_FEAT : -1;
    }
    __syncthreads();

    int dbase = s * DBIG;
    int c0 = tid * 4;
    bool act = (c0 < NC);                // threads 0..249 compute
    bool g1 = (nrows > 8);
    const float* wp = ew + ((size_t)e * D_FEAT + dbase) * NC + c0;

    float4 acc[RB];
#pragma unroll
    for (int r = 0; r < RB; ++r) acc[r] = make_float4(0.f, 0.f, 0.f, 0.f);

    float4 wA0, wA1, wA2, wA3;
    if (act) {
        wA0 = *(const float4*)(wp);
        wA1 = *(const float4*)(wp + (size_t)NC);
        wA2 = *(const float4*)(wp + (size_t)2 * NC);
        wA3 = *(const float4*)(wp + (size_t)3 * NC);
    }

    for (int sub = 0; sub < NSUB; ++sub) {
        // stage h rows [RB x DSUB] into LDS (zeros for invalid rows)
        for (int i = tid; i < RB * NIT4; i += 256) {
            int r = i / NIT4;
            int q = i - r * NIT4;
            int ro = roff_s[r];
            float4 v = make_float4(0.f, 0.f, 0.f, 0.f);
            if (ro >= 0) v = *(const float4*)(h + ro + dbase + sub * DSUB + q * 4);
            *(float4*)&h_lds[r * DSUB + q * 4] = v;
        }
        __syncthreads();

        if (act) {
            for (int it = 0; it < NIT4; ++it) {
                bool last = (sub == NSUB - 1) && (it == NIT4 - 1);
                const float* np = wp + (size_t)4 * NC;
                float4 wB0, wB1, wB2, wB3;
                if (!last) {
                    wB0 = *(const float4*)(np);
                    wB1 = *(const float4*)(np + (size_t)NC);
                    wB2 = *(const float4*)(np + (size_t)2 * NC);
                    wB3 = *(const float4*)(np + (size_t)3 * NC);
                }
                const float* hp = &h_lds[it * 4];
#pragma unroll
                for (int r = 0; r < 8; ++r) {
                    float4 hv = *(const float4*)(hp + r * DSUB);
                    FMA_ROW(acc[r], hv, wA0, wA1, wA2, wA3);
                }
                if (g1) {
#pragma unroll
                    for (int r = 8; r < 16; ++r) {
                        float4 hv = *(const float4*)(hp + r * DSUB);
                        FMA_ROW(acc[r], hv, wA0, wA1, wA2, wA3);
                    }
                }
                wp = np;
                wA0 = wB0; wA1 = wB1; wA2 = wB2; wA3 = wB3;
            }
        }
        __syncthreads();
    }

    if (act) {
#pragma unroll
        for (int r = 0; r < RB; ++r) {
            if (r < nrows) {
                int pos = e * 128 + rbase + r;
                float wgt = rowW[pos];
                int ri = rowIdx[pos];
                int kk = rowK[pos];
                float4 o = make_float4(wgt * acc[r].x, wgt * acc[r].y,
                                       wgt * acc[r].z, wgt * acc[r].w);
                *(float4*)&part[(((size_t)s * 128 + ri) * 2 + kk) * NC + c0] = o;
            }
        }
    }
}

// ---------------- K5: sum partials (8 slices, unroll-4) + weighted bias, softmax
__global__ __launch_bounds__(256) void k5_softmax(
    const float* __restrict__ part, const float* __restrict__ eb,
    const int* __restrict__ top2e, const float* __restrict__ top2w,
    float* __restrict__ out)
{
    int b = blockIdx.x;
    int tid = threadIdx.x;
    __shared__ float red[4];

    int e0 = top2e[b * 2], e1 = top2e[b * 2 + 1];
    float tw0 = top2w[b * 2], tw1 = top2w[b * 2 + 1];

    bool act = (tid < 250);
    int c0 = tid * 4;
    float4 v = make_float4(-1e30f, -1e30f, -1e30f, -1e30f);
    if (act) {
        float4 a0 = make_float4(0.f, 0.f, 0.f, 0.f);
        float4 a1 = a0, a2 = a0, a3 = a0;
        for (int s = 0; s < S8; s += 4) {
            const float* p0 = part + (((size_t)(s + 0) * 128 + b) * 2) * NC + c0;
            const float* p1 = part + (((size_t)(s + 1) * 128 + b) * 2) * NC + c0;
            const float* p2 = part + (((size_t)(s + 2) * 128 + b) * 2) * NC + c0;
            const float* p3 = part + (((size_t)(s + 3) * 128 + b) * 2) * NC + c0;
            float4 q00 = *(const float4*)p0;
            float4 q01 = *(const float4*)(p0 + NC);
            float4 q10 = *(const float4*)p1;
            float4 q11 = *(const float4*)(p1 + NC);
            float4 q20 = *(const float4*)p2;
            float4 q21 = *(const float4*)(p2 + NC);
            float4 q30 = *(const float4*)p3;
            float4 q31 = *(const float4*)(p3 + NC);
            a0.x += q00.x + q01.x; a0.y += q00.y + q01.y;
            a0.z += q00.z + q01.z; a0.w += q00.w + q01.w;
            a1.x += q10.x + q11.x; a1.y += q10.y + q11.y;
            a1.z += q10.z + q11.z; a1.w += q10.w + q11.w;
            a2.x += q20.x + q21.x; a2.y += q20.y + q21.y;
            a2.z += q20.z + q21.z; a2.w += q20.w + q21.w;
            a3.x += q30.x + q31.x; a3.y += q30.y + q31.y;
            a3.z += q30.z + q31.z; a3.w += q30.w + q31.w;
        }
        float4 a = make_float4(a0.x + a1.x + a2.x + a3.x,
                               a0.y + a1.y + a2.y + a3.y,
                               a0.z + a1.z + a2.z + a3.z,
                               a0.w + a1.w + a2.w + a3.w);
        float4 b0 = *(const float4*)(eb + e0 * NC + c0);
        float4 b1 = *(const float4*)(eb + e1 * NC + c0);
        v.x = a.x + tw0 * b0.x + tw1 * b1.x;
        v.y = a.y + tw0 * b0.y + tw1 * b1.y;
        v.z = a.z + tw0 * b0.z + tw1 * b1.z;
        v.w = a.w + tw0 * b0.w + tw1 * b1.w;
    }

    float m = fmaxf(fmaxf(v.x, v.y), fmaxf(v.z, v.w));
#pragma unroll
    for (int off = 32; off >= 1; off >>= 1)
        m = fmaxf(m, __shfl_xor(m, off, 64));
    int wid = tid >> 6, ln = tid & 63;
    if (ln == 0) red[wid] = m;
    __syncthreads();
    m = fmaxf(fmaxf(red[0], red[1]), fmaxf(red[2], red[3]));
    __syncthreads();

    float ex, ey, ez, ew2;
    ex = act ? expf(v.x - m) : 0.f;
    ey = act ? expf(v.y - m) : 0.f;
    ez = act ? expf(v.z - m) : 0.f;
    ew2 = act ? expf(v.w - m) : 0.f;
    float ssum = ex + ey + ez + ew2;
#pragma unroll
    for (int off = 32; off >= 1; off >>= 1)
        ssum += __shfl_xor(ssum, off, 64);
    if (ln == 0) red[wid] = ssum;
    __syncthreads();
    ssum = red[0] + red[1] + red[2] + red[3];
    float inv = 1.f / ssum;

    if (act) {
        float4 o = make_float4(ex * inv, ey * inv, ez * inv, ew2 * inv);
        *(float4*)&out[(size_t)b * NC + c0] = o;
    }
}

extern "C" void kernel_launch(void* const* d_in, const int* in_sizes, int n_in,
                              void* d_out, int out_size, void* d_ws, size_t ws_size,
                              hipStream_t stream) {
    const float* x   = (const float*)d_in[0];
    const float* c1w = (const float*)d_in[1];
    const float* c1b = (const float*)d_in[2];
    const float* c2w = (const float*)d_in[3];
    const float* c2b = (const float*)d_in[4];
    const float* gw  = (const float*)d_in[5];
    const float* gb  = (const float*)d_in[6];
    const float* ew  = (const float*)d_in[7];
    const float* eb  = (const float*)d_in[8];
    float* out = (float*)d_out;

    char* ws = (char*)d_ws;
    // layout (part overlays dead h1 region):
    //   smalls:  0 .. 16384
    //   h:       16384 .. 6438912                  (6,422,528 B)
    //   h1:      6438912 .. 22183936               (15,745,024 B, dead after k2)
    //   part:    6438912 .. 14630912               (8,192,000 B, alive k4..k5)
    int*   cnt    = (int*)  (ws + 0);        //    32 B
    int*   rowIdx = (int*)  (ws + 64);       //  4096 B
    float* rowW   = (float*)(ws + 4160);     //  4096 B
    int*   rowK   = (int*)  (ws + 8256);     //  4096 B
    int*   top2e  = (int*)  (ws + 12352);    //  1024 B
    float* top2w  = (float*)(ws + 13376);    //  1024 B
    float* h      = (float*)(ws + 16384);
    float* h1     = (float*)(ws + 6438912);
    float* part   = (float*)(ws + 6438912);

    k1_conv1<<<128 * 31 * 4, 256, 0, stream>>>(x, c1w, c1b, h1, cnt);
    k2_conv2<<<128 * 14 * 2, 448, 0, stream>>>(h1, c2w, c2b, h);
    k3_gate<<<128, 256, 0, stream>>>(h, gw, gb, cnt, rowIdx, rowW, rowK, top2e, top2w);
    k4_expert<<<8 * 8 * 8, 256, 0, stream>>>(h, ew, cnt, rowIdx, rowW, rowK, part);
    k5_softmax<<<128, 256, 0, stream>>>(part, eb, top2e, top2w, out);
}

// Round 18
// 294.109 us; speedup vs baseline: 1.5880x; 1.5880x over previous
//
#include <hip/hip_runtime.h>
#include <math.h>

#define D_FEAT 12544
#define NC 1000
#define RB 8           // rows per k4 tier
#define S4 32          // global D slices
#define DSLICE 392     // D_FEAT / S4
#define NIT (DSLICE/4) // 98 d4 iterations

// ---------------- K1: conv1(1->32,3x3,VALID)+ReLU+maxpool2 -> h1[128,31,31,32]
__global__ __launch_bounds__(256) void k1_conv1(
    const float* __restrict__ x, const float* __restrict__ w,
    const float* __restrict__ bias, float* __restrict__ h1,
    int* __restrict__ cnt)
{
    // zero routing counters (stream-ordered before k3)
    if (blockIdx.x == 0 && threadIdx.x < 8) cnt[threadIdx.x] = 0;

    int co  = threadIdx.x & 31;
    int pxi = threadIdx.x >> 5;          // 0..7
    int blk = blockIdx.x;
    int pxg = blk & 3;
    int py  = (blk >> 2) % 31;
    int b   = blk / (31 * 4);
    int px  = pxg * 8 + pxi;
    if (px >= 31) return;

    float wr[9];
#pragma unroll
    for (int t = 0; t < 9; ++t) wr[t] = w[t * 32 + co];
    float bb = bias[co];

    float in[4][4];
    const float* xb = x + ((size_t)(b * 64 + 2 * py) * 64 + 2 * px);
#pragma unroll
    for (int r = 0; r < 4; ++r)
#pragma unroll
        for (int c = 0; c < 4; ++c)
            in[r][c] = xb[r * 64 + c];

    float a00 = 0.f, a01 = 0.f, a10 = 0.f, a11 = 0.f;
#pragma unroll
    for (int ky = 0; ky < 3; ++ky)
#pragma unroll
        for (int kx = 0; kx < 3; ++kx) {
            float wv = wr[ky * 3 + kx];
            a00 = fmaf(in[ky][kx],     wv, a00);
            a01 = fmaf(in[ky][kx + 1], wv, a01);
            a10 = fmaf(in[ky + 1][kx], wv, a10);
            a11 = fmaf(in[ky + 1][kx + 1], wv, a11);
        }
    a00 = fmaxf(a00 + bb, 0.f);
    a01 = fmaxf(a01 + bb, 0.f);
    a10 = fmaxf(a10 + bb, 0.f);
    a11 = fmaxf(a11 + bb, 0.f);
    float v = fmaxf(fmaxf(a00, a01), fmaxf(a10, a11));
    h1[((size_t)(b * 31 + py) * 31 + px) * 32 + co] = v;
}

// ---------------- K2: conv2(32->64,3x3,VALID)+ReLU+maxpool2 -> h[128,14,14,64]
__global__ __launch_bounds__(448) void k2_conv2(
    const float* __restrict__ h1, const float* __restrict__ w2,
    const float* __restrict__ b2, float* __restrict__ h)
{
    __shared__ float wl[9 * 32 * 32];    // [tap][ci][co_local] 36864 B

    int co  = threadIdx.x & 31;
    int px  = threadIdx.x >> 5;          // 0..13
    int blk = blockIdx.x;
    int cob = blk & 1;
    int py  = (blk >> 1) % 14;
    int b   = blk / 28;

    for (int i = threadIdx.x; i < 9 * 32 * 32; i += 448) {
        int tapci = i >> 5;
        int col   = i & 31;
        wl[i] = w2[tapci * 64 + cob * 32 + col];
    }
    __syncthreads();

    float acc00 = 0.f, acc01 = 0.f, acc10 = 0.f, acc11 = 0.f;
    const float* base = h1 + ((size_t)(b * 31 + 2 * py) * 31 + 2 * px) * 32;

    for (int q = 0; q < 8; ++q) {
        float4 in4[4][4];
#pragma unroll
        for (int r = 0; r < 4; ++r)
#pragma unroll
            for (int c = 0; c < 4; ++c)
                in4[r][c] = *(const float4*)(base + (r * 31 + c) * 32 + q * 4);

#pragma unroll
        for (int ky = 0; ky < 3; ++ky)
#pragma unroll
            for (int kx = 0; kx < 3; ++kx) {
                int tap = ky * 3 + kx;
                const float* wp = &wl[(tap * 32 + q * 4) * 32 + co];
                float w0 = wp[0];
                float w1 = wp[32];
                float w2v = wp[64];
                float w3 = wp[96];
                acc00 = fmaf(in4[ky][kx].x, w0, acc00);
                acc00 = fmaf(in4[ky][kx].y, w1, acc00);
                acc00 = fmaf(in4[ky][kx].z, w2v, acc00);
                acc00 = fmaf(in4[ky][kx].w, w3, acc00);
                acc01 = fmaf(in4[ky][kx + 1].x, w0, acc01);
                acc01 = fmaf(in4[ky][kx + 1].y, w1, acc01);
                acc01 = fmaf(in4[ky][kx + 1].z, w2v, acc01);
                acc01 = fmaf(in4[ky][kx + 1].w, w3, acc01);
                acc10 = fmaf(in4[ky + 1][kx].x, w0, acc10);
                acc10 = fmaf(in4[ky + 1][kx].y, w1, acc10);
                acc10 = fmaf(in4[ky + 1][kx].z, w2v, acc10);
                acc10 = fmaf(in4[ky + 1][kx].w, w3, acc10);
                acc11 = fmaf(in4[ky + 1][kx + 1].x, w0, acc11);
                acc11 = fmaf(in4[ky + 1][kx + 1].y, w1, acc11);
                acc11 = fmaf(in4[ky + 1][kx + 1].z, w2v, acc11);
                acc11 = fmaf(in4[ky + 1][kx + 1].w, w3, acc11);
            }
    }

    float bb = b2[cob * 32 + co];
    acc00 = fmaxf(acc00 + bb, 0.f);
    acc01 = fmaxf(acc01 + bb, 0.f);
    acc10 = fmaxf(acc10 + bb, 0.f);
    acc11 = fmaxf(acc11 + bb, 0.f);
    float v = fmaxf(fmaxf(acc00, acc01), fmaxf(acc10, acc11));
    h[(size_t)b * D_FEAT + (py * 14 + px) * 64 + cob * 32 + co] = v;
}

// ---------------- K3: gate logits (vectorized float4) + softmax + top2 + routing
__global__ __launch_bounds__(256) void k3_gate(
    const float* __restrict__ h, const float* __restrict__ gw,
    const float* __restrict__ gb, int* __restrict__ cnt,
    int* __restrict__ rowIdx, float* __restrict__ rowW,
    int* __restrict__ rowK, int* __restrict__ top2e, float* __restrict__ top2w)
{
    int b = blockIdx.x;
    int tid = threadIdx.x;
    float acc[8];
#pragma unroll
    for (int e = 0; e < 8; ++e) acc[e] = 0.f;

    const float* hb = h + (size_t)b * D_FEAT;
    for (int i4 = tid; i4 < D_FEAT / 4; i4 += 256) {
        float4 hv = *(const float4*)(hb + i4 * 4);
        const float* gp = gw + (size_t)i4 * 32;
        float4 g0 = *(const float4*)(gp);
        float4 g1 = *(const float4*)(gp + 4);
        float4 g2 = *(const float4*)(gp + 8);
        float4 g3 = *(const float4*)(gp + 12);
        float4 g4 = *(const float4*)(gp + 16);
        float4 g5 = *(const float4*)(gp + 20);
        float4 g6 = *(const float4*)(gp + 24);
        float4 g7 = *(const float4*)(gp + 28);

        acc[0] = fmaf(hv.x, g0.x, acc[0]); acc[0] = fmaf(hv.y, g2.x, acc[0]);
        acc[0] = fmaf(hv.z, g4.x, acc[0]); acc[0] = fmaf(hv.w, g6.x, acc[0]);
        acc[1] = fmaf(hv.x, g0.y, acc[1]); acc[1] = fmaf(hv.y, g2.y, acc[1]);
        acc[1] = fmaf(hv.z, g4.y, acc[1]); acc[1] = fmaf(hv.w, g6.y, acc[1]);
        acc[2] = fmaf(hv.x, g0.z, acc[2]); acc[2] = fmaf(hv.y, g2.z, acc[2]);
        acc[2] = fmaf(hv.z, g4.z, acc[2]); acc[2] = fmaf(hv.w, g6.z, acc[2]);
        acc[3] = fmaf(hv.x, g0.w, acc[3]); acc[3] = fmaf(hv.y, g2.w, acc[3]);
        acc[3] = fmaf(hv.z, g4.w, acc[3]); acc[3] = fmaf(hv.w, g6.w, acc[3]);
        acc[4] = fmaf(hv.x, g1.x, acc[4]); acc[4] = fmaf(hv.y, g3.x, acc[4]);
        acc[4] = fmaf(hv.z, g5.x, acc[4]); acc[4] = fmaf(hv.w, g7.x, acc[4]);
        acc[5] = fmaf(hv.x, g1.y, acc[5]); acc[5] = fmaf(hv.y, g3.y, acc[5]);
        acc[5] = fmaf(hv.z, g5.y, acc[5]); acc[5] = fmaf(hv.w, g7.y, acc[5]);
        acc[6] = fmaf(hv.x, g1.z, acc[6]); acc[6] = fmaf(hv.y, g3.z, acc[6]);
        acc[6] = fmaf(hv.z, g5.z, acc[6]); acc[6] = fmaf(hv.w, g7.z, acc[6]);
        acc[7] = fmaf(hv.x, g1.w, acc[7]); acc[7] = fmaf(hv.y, g3.w, acc[7]);
        acc[7] = fmaf(hv.z, g5.w, acc[7]); acc[7] = fmaf(hv.w, g7.w, acc[7]);
    }

#pragma unroll
    for (int e = 0; e < 8; ++e) {
        float v = acc[e];
        v += __shfl_down(v, 32, 64);
        v += __shfl_down(v, 16, 64);
        v += __shfl_down(v, 8, 64);
        v += __shfl_down(v, 4, 64);
        v += __shfl_down(v, 2, 64);
        v += __shfl_down(v, 1, 64);
        acc[e] = v;
    }

    __shared__ float sm[4][8];
    int wid = tid >> 6, ln = tid & 63;
    if (ln == 0) {
#pragma unroll
        for (int e = 0; e < 8; ++e) sm[wid][e] = acc[e];
    }
    __syncthreads();

    if (tid == 0) {
        float lg[8], p[8];
        float m = -1e30f;
#pragma unroll
        for (int e = 0; e < 8; ++e) {
            lg[e] = sm[0][e] + sm[1][e] + sm[2][e] + sm[3][e] + gb[e];
            m = fmaxf(m, lg[e]);
        }
        float s = 0.f;
#pragma unroll
        for (int e = 0; e < 8; ++e) { p[e] = expf(lg[e] - m); s += p[e]; }
        float inv = 1.f / s;
#pragma unroll
        for (int e = 0; e < 8; ++e) p[e] *= inv;

        int i0 = 0;
#pragma unroll
        for (int e = 1; e < 8; ++e) if (p[e] > p[i0]) i0 = e;
        int i1 = (i0 == 0) ? 1 : 0;
#pragma unroll
        for (int e = 0; e < 8; ++e) if (e != i0 && p[e] > p[i1]) i1 = e;

        int pos0 = atomicAdd(&cnt[i0], 1);
        rowIdx[i0 * 128 + pos0] = b;
        rowW[i0 * 128 + pos0] = p[i0];
        rowK[i0 * 128 + pos0] = 0;
        int pos1 = atomicAdd(&cnt[i1], 1);
        rowIdx[i1 * 128 + pos1] = b;
        rowW[i1 * 128 + pos1] = p[i1];
        rowK[i1 * 128 + pos1] = 1;

        top2e[b * 2]     = i0;
        top2e[b * 2 + 1] = i1;
        top2w[b * 2]     = p[i0];
        top2w[b * 2 + 1] = p[i1];
    }
}

// 8-col FMA: accA/accB (cols 0-3 / 4-7) += hv(4 dims) dot W rows
#define FMA_ROW8(AA, AB, HV, WA0, WB0, WA1, WB1, WA2, WB2, WA3, WB3)  \
    do {                                                        \
        (AA).x = fmaf((HV).x, (WA0).x, (AA).x);                 \
        (AA).x = fmaf((HV).y, (WA1).x, (AA).x);                 \
        (AA).x = fmaf((HV).z, (WA2).x, (AA).x);                 \
        (AA).x = fmaf((HV).w, (WA3).x, (AA).x);                 \
        (AA).y = fmaf((HV).x, (WA0).y, (AA).y);                 \
        (AA).y = fmaf((HV).y, (WA1).y, (AA).y);                 \
        (AA).y = fmaf((HV).z, (WA2).y, (AA).y);                 \
        (AA).y = fmaf((HV).w, (WA3).y, (AA).y);                 \
        (AA).z = fmaf((HV).x, (WA0).z, (AA).z);                 \
        (AA).z = fmaf((HV).y, (WA1).z, (AA).z);                 \
        (AA).z = fmaf((HV).z, (WA2).z, (AA).z);                 \
        (AA).z = fmaf((HV).w, (WA3).z, (AA).z);                 \
        (AA).w = fmaf((HV).x, (WA0).w, (AA).w);                 \
        (AA).w = fmaf((HV).y, (WA1).w, (AA).w);                 \
        (AA).w = fmaf((HV).z, (WA2).w, (AA).w);                 \
        (AA).w = fmaf((HV).w, (WA3).w, (AA).w);                 \
        (AB).x = fmaf((HV).x, (WB0).x, (AB).x);                 \
        (AB).x = fmaf((HV).y, (WB1).x, (AB).x);                 \
        (AB).x = fmaf((HV).z, (WB2).x, (AB).x);                 \
        (AB).x = fmaf((HV).w, (WB3).x, (AB).x);                 \
        (AB).y = fmaf((HV).x, (WB0).y, (AB).y);                 \
        (AB).y = fmaf((HV).y, (WB1).y, (AB).y);                 \
        (AB).y = fmaf((HV).z, (WB2).y, (AB).y);                 \
        (AB).y = fmaf((HV).w, (WB3).y, (AB).y);                 \
        (AB).z = fmaf((HV).x, (WB0).z, (AB).z);                 \
        (AB).z = fmaf((HV).y, (WB1).z, (AB).z);                 \
        (AB).z = fmaf((HV).z, (WB2).z, (AB).z);                 \
        (AB).z = fmaf((HV).w, (WB3).z, (AB).z);                 \
        (AB).w = fmaf((HV).x, (WB0).w, (AB).w);                 \
        (AB).w = fmaf((HV).y, (WB1).w, (AB).w);                 \
        (AB).w = fmaf((HV).z, (WB2).w, (AB).w);                 \
        (AB).w = fmaf((HV).w, (WB3).w, (AB).w);                 \
    } while (0)

// ---------------- K4: grouped expert GEMM — 8 cols/thread (halved LDS-read term)
// grid = rc(16, HIGH bits, sparse) x e(8) x s(32, LOW bits -> XCDs).
// block 128 thr (125 active x 8 cols via 2x float4); 8 rows in LDS (12.5 KB).
// Per wave-step: 8 ds_read_b128 + 256 FMA -> VALU-dominant, LDS term ~33 us.
__global__ __launch_bounds__(128) void k4_expert(
    const float* __restrict__ h, const float* __restrict__ ew,
    const int* __restrict__ cnt, const int* __restrict__ rowIdx,
    const float* __restrict__ rowW, const int* __restrict__ rowK,
    float* __restrict__ part)
{
    __shared__ float h_lds[RB * DSLICE];        // 12544 B
    __shared__ int   roff_s[RB];

    int tid = threadIdx.x;
    int bid = blockIdx.x;
    int s  = bid & 31;                   // LOW bits: uniform across XCDs
    int e  = (bid >> 5) & 7;
    int rc = bid >> 8;                   // HIGH bits: sparse early-exit (0..15)

    int n = cnt[e];
    int rbase = rc * RB;
    if (rbase >= n) return;
    int nrows = n - rbase; if (nrows > RB) nrows = RB;

    if (tid < RB) {
        roff_s[tid] = (tid < nrows) ? rowIdx[e * 128 + rbase + tid] * D_FEAT : -1;
    }
    __syncthreads();

    int dbase = s * DSLICE;
    // stage h rows [RB x DSLICE] into LDS (zeros for invalid rows)
    for (int i = tid; i < RB * NIT; i += 128) {
        int r = i / NIT;
        int q = i - r * NIT;
        int ro = roff_s[r];
        float4 v = make_float4(0.f, 0.f, 0.f, 0.f);
        if (ro >= 0) v = *(const float4*)(h + ro + dbase + q * 4);
        *(float4*)&h_lds[r * DSLICE + q * 4] = v;
    }
    __syncthreads();

    int c0 = tid * 8;
    if (c0 < NC) {                        // threads 0..124 compute
        const float* wp = ew + ((size_t)e * D_FEAT + dbase) * NC + c0;

        float4 accA[RB], accB[RB];
#pragma unroll
        for (int r = 0; r < RB; ++r) {
            accA[r] = make_float4(0.f, 0.f, 0.f, 0.f);
            accB[r] = make_float4(0.f, 0.f, 0.f, 0.f);
        }

        float4 a0 = *(const float4*)(wp);
        float4 b0 = *(const float4*)(wp + 4);
        float4 a1 = *(const float4*)(wp + (size_t)NC);
        float4 b1 = *(const float4*)(wp + (size_t)NC + 4);
        float4 a2 = *(const float4*)(wp + (size_t)2 * NC);
        float4 b2 = *(const float4*)(wp + (size_t)2 * NC + 4);
        float4 a3 = *(const float4*)(wp + (size_t)3 * NC);
        float4 b3 = *(const float4*)(wp + (size_t)3 * NC + 4);

        for (int it = 0; it < NIT; ++it) {
            const float* np = wp + (size_t)4 * NC;
            float4 na0, nb0, na1, nb1, na2, nb2, na3, nb3;
            if (it < NIT - 1) {
                na0 = *(const float4*)(np);
                nb0 = *(const float4*)(np + 4);
                na1 = *(const float4*)(np + (size_t)NC);
                nb1 = *(const float4*)(np + (size_t)NC + 4);
                na2 = *(const float4*)(np + (size_t)2 * NC);
                nb2 = *(const float4*)(np + (size_t)2 * NC + 4);
                na3 = *(const float4*)(np + (size_t)3 * NC);
                nb3 = *(const float4*)(np + (size_t)3 * NC + 4);
            }
            const float* hp = &h_lds[it * 4];
#pragma unroll
            for (int r = 0; r < RB; ++r) {       // unconditional: pad rows zero
                float4 hv = *(const float4*)(hp + r * DSLICE);
                FMA_ROW8(accA[r], accB[r], hv, a0, b0, a1, b1, a2, b2, a3, b3);
            }
            wp = np;
            a0 = na0; b0 = nb0; a1 = na1; b1 = nb1;
            a2 = na2; b2 = nb2; a3 = na3; b3 = nb3;
        }

#pragma unroll
        for (int r = 0; r < RB; ++r) {
            if (r < nrows) {
                int pos = e * 128 + rbase + r;
                float wgt = rowW[pos];
                int ri = rowIdx[pos];
                int kk = rowK[pos];
                float* op = &part[(((size_t)s * 128 + ri) * 2 + kk) * NC + c0];
                float4 oA = make_float4(wgt * accA[r].x, wgt * accA[r].y,
                                        wgt * accA[r].z, wgt * accA[r].w);
                float4 oB = make_float4(wgt * accB[r].x, wgt * accB[r].y,
                                        wgt * accB[r].z, wgt * accB[r].w);
                *(float4*)(op) = oA;
                *(float4*)(op + 4) = oB;
            }
        }
    }
}

// ---------------- K5: sum partials (unroll-4) + weighted bias, row softmax
__global__ __launch_bounds__(256) void k5_softmax(
    const float* __restrict__ part, const float* __restrict__ eb,
    const int* __restrict__ top2e, const float* __restrict__ top2w,
    float* __restrict__ out)
{
    int b = blockIdx.x;
    int tid = threadIdx.x;
    __shared__ float red[4];

    int e0 = top2e[b * 2], e1 = top2e[b * 2 + 1];
    float tw0 = top2w[b * 2], tw1 = top2w[b * 2 + 1];

    bool act = (tid < 250);
    int c0 = tid * 4;
    float4 v = make_float4(-1e30f, -1e30f, -1e30f, -1e30f);
    if (act) {
        float4 a0 = make_float4(0.f, 0.f, 0.f, 0.f);
        float4 a1 = a0, a2 = a0, a3 = a0;
        for (int s = 0; s < S4; s += 4) {
            const float* p0 = part + (((size_t)(s + 0) * 128 + b) * 2) * NC + c0;
            const float* p1 = part + (((size_t)(s + 1) * 128 + b) * 2) * NC + c0;
            const float* p2 = part + (((size_t)(s + 2) * 128 + b) * 2) * NC + c0;
            const float* p3 = part + (((size_t)(s + 3) * 128 + b) * 2) * NC + c0;
            float4 q00 = *(const float4*)p0;
            float4 q01 = *(const float4*)(p0 + NC);
            float4 q10 = *(const float4*)p1;
            float4 q11 = *(const float4*)(p1 + NC);
            float4 q20 = *(const float4*)p2;
            float4 q21 = *(const float4*)(p2 + NC);
            float4 q30 = *(const float4*)p3;
            float4 q31 = *(const float4*)(p3 + NC);
            a0.x += q00.x + q01.x; a0.y += q00.y + q01.y;
            a0.z += q00.z + q01.z; a0.w += q00.w + q01.w;
            a1.x += q10.x + q11.x; a1.y += q10.y + q11.y;
            a1.z += q10.z + q11.z; a1.w += q10.w + q11.w;
            a2.x += q20.x + q21.x; a2.y += q20.y + q21.y;
            a2.z += q20.z + q21.z; a2.w += q20.w + q21.w;
            a3.x += q30.x + q31.x; a3.y += q30.y + q31.y;
            a3.z += q30.z + q31.z; a3.w += q30.w + q31.w;
        }
        float4 a = make_float4(a0.x + a1.x + a2.x + a3.x,
                               a0.y + a1.y + a2.y + a3.y,
                               a0.z + a1.z + a2.z + a3.z,
                               a0.w + a1.w + a2.w + a3.w);
        float4 b0 = *(const float4*)(eb + e0 * NC + c0);
        float4 b1 = *(const float4*)(eb + e1 * NC + c0);
        v.x = a.x + tw0 * b0.x + tw1 * b1.x;
        v.y = a.y + tw0 * b0.y + tw1 * b1.y;
        v.z = a.z + tw0 * b0.z + tw1 * b1.z;
        v.w = a.w + tw0 * b0.w + tw1 * b1.w;
    }

    float m = fmaxf(fmaxf(v.x, v.y), fmaxf(v.z, v.w));
#pragma unroll
    for (int off = 32; off >= 1; off >>= 1)
        m = fmaxf(m, __shfl_xor(m, off, 64));
    int wid = tid >> 6, ln = tid & 63;
    if (ln == 0) red[wid] = m;
    __syncthreads();
    m = fmaxf(fmaxf(red[0], red[1]), fmaxf(red[2], red[3]));
    __syncthreads();

    float ex, ey, ez, ew2;
    ex = act ? expf(v.x - m) : 0.f;
    ey = act ? expf(v.y - m) : 0.f;
    ez = act ? expf(v.z - m) : 0.f;
    ew2 = act ? expf(v.w - m) : 0.f;
    float ssum = ex + ey + ez + ew2;
#pragma unroll
    for (int off = 32; off >= 1; off >>= 1)
        ssum += __shfl_xor(ssum, off, 64);
    if (ln == 0) red[wid] = ssum;
    __syncthreads();
    ssum = red[0] + red[1] + red[2] + red[3];
    float inv = 1.f / ssum;

    if (act) {
        float4 o = make_float4(ex * inv, ey * inv, ez * inv, ew2 * inv);
        *(float4*)&out[(size_t)b * NC + c0] = o;
    }
}

extern "C" void kernel_launch(void* const* d_in, const int* in_sizes, int n_in,
                              void* d_out, int out_size, void* d_ws, size_t ws_size,
                              hipStream_t stream) {
    const float* x   = (const float*)d_in[0];
    const float* c1w = (const float*)d_in[1];
    const float* c1b = (const float*)d_in[2];
    const float* c2w = (const float*)d_in[3];
    const float* c2b = (const float*)d_in[4];
    const float* gw  = (const float*)d_in[5];
    const float* gb  = (const float*)d_in[6];
    const float* ew  = (const float*)d_in[7];
    const float* eb  = (const float*)d_in[8];
    float* out = (float*)d_out;

    char* ws = (char*)d_ws;
    // layout (part overlays dead h1 region):
    //   smalls:  0 .. 16384
    //   h:       16384 .. 6438912                  (6,422,528 B)
    //   h1:      6438912 .. 22183936               (15,745,024 B, dead after k2)
    //   part:    6438912 .. 39206912               (32,768,000 B, alive k4..k5)
    int*   cnt    = (int*)  (ws + 0);        //    32 B
    int*   rowIdx = (int*)  (ws + 64);       //  4096 B
    float* rowW   = (float*)(ws + 4160);     //  4096 B
    int*   rowK   = (int*)  (ws + 8256);     //  4096 B
    int*   top2e  = (int*)  (ws + 12352);    //  1024 B
    float* top2w  = (float*)(ws + 13376);    //  1024 B
    float* h      = (float*)(ws + 16384);
    float* h1     = (float*)(ws + 6438912);
    float* part   = (float*)(ws + 6438912);

    k1_conv1<<<128 * 31 * 4, 256, 0, stream>>>(x, c1w, c1b, h1, cnt);
    k2_conv2<<<128 * 14 * 2, 448, 0, stream>>>(h1, c2w, c2b, h);
    k3_gate<<<128, 256, 0, stream>>>(h, gw, gb, cnt, rowIdx, rowW, rowK, top2e, top2w);
    k4_expert<<<S4 * 8 * 16, 128, 0, stream>>>(h, ew, cnt, rowIdx, rowW, rowK, part);
    k5_softmax<<<128, 256, 0, stream>>>(part, eb, top2e, top2w, out);
}